// Round 1
// baseline (8042.858 us; speedup 1.0000x reference)
//
#include <hip/hip_runtime.h>

#define B_ 8
#define T_ 14
#define HH 64
#define WW 64
#define CC 64
#define FF 64
#define IMG (HH*WW*CC)  // 262144 elements per (b,t) image

__device__ __forceinline__ float hsig(float z) {
    return fminf(fmaxf(fmaf(z, 0.2f, 0.5f), 0.0f), 1.0f);
}

// One ConvLSTM timestep. Raw h_t is stored into out[:, t]; h_{t-1} is read
// from out[:, t-1]. Residual (+x) is applied by a separate final kernel.
// Block: (b, y, 16 consecutive x-columns). 256 threads = 4 waves.
// Lane = output channel f (0..63); wave g handles 4 x-positions.
template<bool FIRST>
__global__ __launch_bounds__(256) void lstm_step(
    const float* __restrict__ x,     // [8,14,64,64,64]
    const float* __restrict__ Wx,    // [3,3,64,256] gate order i,f,g,o
    const float* __restrict__ Wh,    // [3,3,64,256]
    const float* __restrict__ bias,  // [256]
    float* __restrict__ out,         // [8,14,64,64,64] holds raw h per t
    float* __restrict__ cst,         // [8,64,64,64] cell state (d_ws)
    int t)
{
    const int tid = threadIdx.x;
    const int f = tid & 63;
    const int g = tid >> 6;
    const int bq = blockIdx.x;
    const int xq = bq & 3;          // which 16-column strip
    const int y  = (bq >> 2) & 63;
    const int b  = bq >> 8;
    const int x0 = xq * 16 + g * 4; // this wave's first column

    float z[16];  // [gate][pos], gates i,f,g,o
    #pragma unroll
    for (int gate = 0; gate < 4; ++gate) {
        float bb = bias[gate * 64 + f];
        z[gate*4+0] = bb; z[gate*4+1] = bb; z[gate*4+2] = bb; z[gate*4+3] = bb;
    }

    const float* xbase = x + (size_t)(b * T_ + t) * IMG;
    const float* hbase = FIRST ? x : (out + (size_t)(b * T_ + (t - 1)) * IMG);

    for (int ky = 0; ky < 3; ++ky) {
        int iy = y + ky - 1;
        if ((unsigned)iy >= (unsigned)HH) continue;
        const float* xrow = xbase + iy * (WW * CC);
        const float* hrow = hbase + iy * (WW * CC);
        #pragma unroll
        for (int kx = 0; kx < 3; ++kx) {
            const float* wxp = Wx + ((ky*3 + kx) * CC) * 256 + f;
            const float* whp = Wh + ((ky*3 + kx) * CC) * 256 + f;
            int ix0 = x0 + kx - 1;
            bool v[4];
            const float* xp[4];
            const float* hp[4];
            #pragma unroll
            for (int p = 0; p < 4; ++p) {
                int ix = ix0 + p;
                v[p] = ((unsigned)ix < (unsigned)WW);
                int off = v[p] ? ix * CC : 0;   // clamp to safe addr, select 0 below
                xp[p] = xrow + off;
                hp[p] = hrow + off;
            }
            #pragma unroll 4
            for (int ci = 0; ci < CC; ++ci) {
                float wxi = wxp[ci*256];
                float wxf = wxp[ci*256 + 64];
                float wxg = wxp[ci*256 + 128];
                float wxo = wxp[ci*256 + 192];
                float whi = 0.f, whf = 0.f, whg = 0.f, who = 0.f;
                if (!FIRST) {
                    whi = whp[ci*256];
                    whf = whp[ci*256 + 64];
                    whg = whp[ci*256 + 128];
                    who = whp[ci*256 + 192];
                }
                #pragma unroll
                for (int p = 0; p < 4; ++p) {
                    float xv = v[p] ? xp[p][ci] : 0.0f;
                    z[0+p]  = fmaf(xv, wxi, z[0+p]);
                    z[4+p]  = fmaf(xv, wxf, z[4+p]);
                    z[8+p]  = fmaf(xv, wxg, z[8+p]);
                    z[12+p] = fmaf(xv, wxo, z[12+p]);
                    if (!FIRST) {
                        float hv = v[p] ? hp[p][ci] : 0.0f;
                        z[0+p]  = fmaf(hv, whi, z[0+p]);
                        z[4+p]  = fmaf(hv, whf, z[4+p]);
                        z[8+p]  = fmaf(hv, whg, z[8+p]);
                        z[12+p] = fmaf(hv, who, z[12+p]);
                    }
                }
            }
        }
    }

    float* outrow = out + (size_t)(b * T_ + t) * IMG + y * (WW * CC);
    #pragma unroll
    for (int p = 0; p < 4; ++p) {
        int xpos = x0 + p;
        int sidx = ((b * HH + y) * WW + xpos) * FF + f;
        float ig = hsig(z[0+p]);
        float fg = hsig(z[4+p]);
        float gg = tanhf(z[8+p]);
        float og = hsig(z[12+p]);
        float cn = FIRST ? (ig * gg) : fmaf(fg, cst[sidx], ig * gg);
        cst[sidx] = cn;
        outrow[xpos * CC + f] = og * tanhf(cn);
    }
}

__global__ void residual_add(const float4* __restrict__ xin,
                             float4* __restrict__ out, int n4) {
    int i = blockIdx.x * blockDim.x + threadIdx.x;
    int stride = gridDim.x * blockDim.x;
    for (; i < n4; i += stride) {
        float4 a = out[i];
        float4 c = xin[i];
        a.x += c.x; a.y += c.y; a.z += c.z; a.w += c.w;
        out[i] = a;
    }
}

extern "C" void kernel_launch(void* const* d_in, const int* in_sizes, int n_in,
                              void* d_out, int out_size, void* d_ws, size_t ws_size,
                              hipStream_t stream) {
    const float* x    = (const float*)d_in[0];
    const float* Wx   = (const float*)d_in[1];
    const float* Wh   = (const float*)d_in[2];
    const float* bias = (const float*)d_in[3];
    float* out = (float*)d_out;
    float* cst = (float*)d_ws;   // 8*64*64*64 fp32 = 8 MB cell state

    const int grid = B_ * HH * 4;  // 2048 blocks: (b, y, 4 strips of 16 cols)
    lstm_step<true><<<grid, 256, 0, stream>>>(x, Wx, Wh, bias, out, cst, 0);
    for (int t = 1; t < T_; ++t) {
        lstm_step<false><<<grid, 256, 0, stream>>>(x, Wx, Wh, bias, out, cst, t);
    }

    const int n4 = B_ * T_ * IMG / 4;  // 7,340,032 float4s
    residual_add<<<8192, 256, 0, stream>>>((const float4*)x, (float4*)out, n4);
}

// Round 2
// 542.289 us; speedup vs baseline: 14.8313x; 14.8313x over previous
//
#include <hip/hip_runtime.h>

#define B_ 8
#define T_ 14
#define HH 64
#define WW 64
#define CC 64
#define FF 64
#define IMG (HH*WW*CC)  // 262144 elems per (b,t) image

typedef __attribute__((ext_vector_type(8))) short short8;
typedef __attribute__((ext_vector_type(4))) float floatx4;

// ws layout (bytes):
//   [0, 589824)                 Wt: bf16 weights in MFMA B-fragment-major order
//   [1 MB, 9 MB)                c state fp32 [8][64][64][64]
//   [9 MB, 13 MB)               h ping bf16 [8][64][64][64]
//   [13 MB, 17 MB)              h pong bf16
#define WT_OFF   0
#define C_OFF    (1u << 20)
#define H0_OFF   (C_OFF + 8u * 1024 * 1024)
#define H1_OFF   (H0_OFF + 4u * 1024 * 1024)

__device__ __forceinline__ unsigned short bf16_of(float f) {
    unsigned int x = __float_as_uint(f);
    unsigned int r = (x + 0x7FFFu + ((x >> 16) & 1u)) >> 16;  // RTNE
    return (unsigned short)r;
}
__device__ __forceinline__ unsigned int pack2(float a, float b) {
    return (unsigned int)bf16_of(a) | ((unsigned int)bf16_of(b) << 16);
}
__device__ __forceinline__ float hsig(float z) {
    return fminf(fmaxf(fmaf(z, 0.2f, 0.5f), 0.0f), 1.0f);
}
__device__ __forceinline__ float tanh_fast(float v) {
    float e = __expf(2.0f * v);
    return 1.0f - 2.0f / (e + 1.0f);
}

// Repack Wx,Wh [3,3,64,256] fp32 -> bf16 B-fragment-major:
// chunk fc = ((src*9+tap)*2+g)*16 + ntile ; element [lane][j] (j=0..7 contiguous)
// value = W[tap*64 + (g*32 + (lane>>4)*8 + j)]*256 + ntile*16 + (lane&15)
__global__ void repack_weights(const float* __restrict__ Wx,
                               const float* __restrict__ Wh,
                               unsigned short* __restrict__ Wt) {
    int u = blockIdx.x * 256 + threadIdx.x;    // 36864 threads
    int l  = u & 63;
    int nt = (u >> 6) & 15;
    int g  = (u >> 10) & 1;
    int st = u >> 11;                          // src*9 + tap, 0..17
    const float* W = (st < 9) ? Wx : Wh;
    int tap = (st < 9) ? st : st - 9;
    int n  = nt * 16 + (l & 15);
    int c0 = g * 32 + (l >> 4) * 8;
    unsigned short tmp[8];
    #pragma unroll
    for (int j = 0; j < 8; ++j) {
        tmp[j] = bf16_of(W[(tap * 64 + c0 + j) * 256 + n]);
    }
    *(uint4*)(Wt + (size_t)u * 8) = *(const uint4*)tmp;
}

// LDS A-tile: bf16 [src 2][ky 3][col 66][ch 64]; col 0 and 65 are zero halo.
#define AT(s, r, col, c) ((((s) * 3 + (r)) * 66 + (col)) * 64 + (c))

// One ConvLSTM timestep as implicit GEMM.
// Block = one image row (b,y): M=64 pixels, N=256 gate-channels, K=18 taps x 64.
// 4 waves; wave w owns gate w (n in [64w, 64w+64)).
template<bool FIRST>
__global__ __launch_bounds__(256, 2) void lstm_step_mfma(
    const float* __restrict__ x,          // [8,14,64,64,64] fp32
    const unsigned short* __restrict__ Wt,// repacked bf16 weights
    const float* __restrict__ bias,       // [256] fp32
    float* __restrict__ out,              // [8,14,64,64,64] fp32 (y = h + x)
    float* __restrict__ cst,              // [8,64,64,64] fp32
    const unsigned short* __restrict__ hprev, // [8,64,64,64] bf16
    unsigned short* __restrict__ hnext,       // [8,64,64,64] bf16
    int t)
{
    __shared__ __align__(16) float smem[64 * 260];   // 66560 B; aliased as A-tile
    unsigned short* aT = (unsigned short*)smem;

    const int tid = threadIdx.x;
    const int l   = tid & 63;
    const int w   = tid >> 6;          // wave id == gate id
    const int y   = blockIdx.x & 63;
    const int b   = blockIdx.x >> 6;
    const int m16 = l & 15;
    const int q   = l >> 4;

    const float* xbase = x + (size_t)(b * T_ + t) * IMG;

    // ---- stage x rows (fp32 -> bf16), 16 elems/thread/row ----
    {
        const int col = (tid >> 2) + 1;
        const int ch  = (tid & 3) * 16;
        #pragma unroll
        for (int r = 0; r < 3; ++r) {
            int iy = y + r - 1;
            uint4 u0 = {0, 0, 0, 0}, u1 = {0, 0, 0, 0};
            if ((unsigned)iy < (unsigned)HH) {
                const float4* s4 = (const float4*)(xbase + iy * (WW * CC)) + tid * 4;
                float4 f0 = s4[0], f1 = s4[1], f2 = s4[2], f3 = s4[3];
                u0.x = pack2(f0.x, f0.y); u0.y = pack2(f0.z, f0.w);
                u0.z = pack2(f1.x, f1.y); u0.w = pack2(f1.z, f1.w);
                u1.x = pack2(f2.x, f2.y); u1.y = pack2(f2.z, f2.w);
                u1.z = pack2(f3.x, f3.y); u1.w = pack2(f3.z, f3.w);
            }
            int off = AT(0, r, col, ch);
            *(uint4*)(aT + off)     = u0;
            *(uint4*)(aT + off + 8) = u1;
        }
        // ---- stage h rows (bf16 copy), or zeros on first step ----
        #pragma unroll
        for (int r = 0; r < 3; ++r) {
            int iy = y + r - 1;
            uint4 u0 = {0, 0, 0, 0}, u1 = {0, 0, 0, 0};
            if (!FIRST && (unsigned)iy < (unsigned)HH) {
                const uint4* hp = (const uint4*)(hprev + (size_t)(b * HH + iy) * (WW * CC));
                u0 = hp[tid * 2];
                u1 = hp[tid * 2 + 1];
            }
            int off = AT(1, r, col, ch);
            *(uint4*)(aT + off)     = u0;
            *(uint4*)(aT + off + 8) = u1;
        }
        // ---- zero halo columns 0 and 65 ----
        if (tid < 96) {
            int grp = tid >> 3, l8 = tid & 7;
            int src = grp / 6, rem = grp % 6;
            int r = rem >> 1, colh = (rem & 1) * 65;
            uint4 z = {0, 0, 0, 0};
            *(uint4*)(aT + AT(src, r, colh, l8 * 8)) = z;
        }
    }
    __syncthreads();

    // ---- accumulators init with bias (bias depends only on column n) ----
    floatx4 acc[4][4];
    #pragma unroll
    for (int nt = 0; nt < 4; ++nt) {
        float bv = bias[w * 64 + nt * 16 + m16];
        #pragma unroll
        for (int mt = 0; mt < 4; ++mt) {
            acc[mt][nt][0] = bv; acc[mt][nt][1] = bv;
            acc[mt][nt][2] = bv; acc[mt][nt][3] = bv;
        }
    }

    // ---- K loop: 9 taps x {x,h} x 2 k-chunks of 32 ----
    const int NSRC = FIRST ? 1 : 2;
    #pragma unroll
    for (int ky = 0; ky < 3; ++ky) {
        #pragma unroll
        for (int kx = 0; kx < 3; ++kx) {
            #pragma unroll
            for (int src = 0; src < NSRC; ++src) {
                #pragma unroll
                for (int g = 0; g < 2; ++g) {
                    short8 af[4];
                    #pragma unroll
                    for (int mt = 0; mt < 4; ++mt) {
                        int col = mt * 16 + m16 + kx;   // 0..65 (halo handles kx-1)
                        af[mt] = *(const short8*)(aT + AT(src, ky, col, g * 32 + q * 8));
                    }
                    short8 bf[4];
                    int fc = (((src * 9 + ky * 3 + kx) * 2 + g) * 16 + w * 4);
                    #pragma unroll
                    for (int nt = 0; nt < 4; ++nt) {
                        bf[nt] = *(const short8*)(Wt + (size_t)(fc + nt) * 512 + l * 8);
                    }
                    #pragma unroll
                    for (int mt = 0; mt < 4; ++mt) {
                        #pragma unroll
                        for (int nt = 0; nt < 4; ++nt) {
                            acc[mt][nt] = __builtin_amdgcn_mfma_f32_16x16x32_bf16(
                                af[mt], bf[nt], acc[mt][nt], 0, 0, 0);
                        }
                    }
                }
            }
        }
    }

    // ---- transpose z through LDS: zT[64 m][260 pad] fp32 ----
    __syncthreads();   // all waves done reading aT
    #pragma unroll
    for (int mt = 0; mt < 4; ++mt) {
        #pragma unroll
        for (int nt = 0; nt < 4; ++nt) {
            int n = w * 64 + nt * 16 + m16;
            #pragma unroll
            for (int r = 0; r < 4; ++r) {
                int m = mt * 16 + q * 4 + r;
                smem[m * 260 + n] = acc[mt][nt][r];
            }
        }
    }
    __syncthreads();

    // ---- gates, cell update, h, fused residual ----
    const int fch   = (tid & 15) * 4;
    const int mbase = tid >> 4;
    const float* xres = xbase + y * (WW * CC);
    float* outrow = out + (size_t)(b * T_ + t) * IMG + y * (WW * CC);
    #pragma unroll
    for (int i = 0; i < 4; ++i) {
        int m = mbase + i * 16;
        const float* zr = smem + m * 260;
        float4 zi = *(const float4*)(zr + fch);
        float4 zf = *(const float4*)(zr + 64 + fch);
        float4 zg = *(const float4*)(zr + 128 + fch);
        float4 zo = *(const float4*)(zr + 192 + fch);
        size_t sidx = (size_t)(b * HH + y) * (WW * CC) + m * 64 + fch;
        float4 cold = {0, 0, 0, 0};
        if (!FIRST) cold = *(const float4*)(cst + sidx);
        float4 xv = *(const float4*)(xres + m * 64 + fch);

        float cn[4], hv[4];
        float zia[4] = {zi.x, zi.y, zi.z, zi.w};
        float zfa[4] = {zf.x, zf.y, zf.z, zf.w};
        float zga[4] = {zg.x, zg.y, zg.z, zg.w};
        float zoa[4] = {zo.x, zo.y, zo.z, zo.w};
        float ca[4]  = {cold.x, cold.y, cold.z, cold.w};
        float xa[4]  = {xv.x, xv.y, xv.z, xv.w};
        #pragma unroll
        for (int k = 0; k < 4; ++k) {
            float ig = hsig(zia[k]);
            float fg = hsig(zfa[k]);
            float gg = tanh_fast(zga[k]);
            float og = hsig(zoa[k]);
            cn[k] = FIRST ? (ig * gg) : fmaf(fg, ca[k], ig * gg);
            hv[k] = og * tanh_fast(cn[k]);
        }
        float4 cnew = {cn[0], cn[1], cn[2], cn[3]};
        *(float4*)(cst + sidx) = cnew;
        ushort4 hb;
        hb.x = bf16_of(hv[0]); hb.y = bf16_of(hv[1]);
        hb.z = bf16_of(hv[2]); hb.w = bf16_of(hv[3]);
        *(ushort4*)(hnext + sidx) = hb;
        float4 yo = {hv[0] + xa[0], hv[1] + xa[1], hv[2] + xa[2], hv[3] + xa[3]};
        *(float4*)(outrow + m * 64 + fch) = yo;
    }
}

extern "C" void kernel_launch(void* const* d_in, const int* in_sizes, int n_in,
                              void* d_out, int out_size, void* d_ws, size_t ws_size,
                              hipStream_t stream) {
    const float* x    = (const float*)d_in[0];
    const float* Wx   = (const float*)d_in[1];
    const float* Wh   = (const float*)d_in[2];
    const float* bias = (const float*)d_in[3];
    float* out = (float*)d_out;

    unsigned short* Wt = (unsigned short*)((char*)d_ws + WT_OFF);
    float* cst         = (float*)((char*)d_ws + C_OFF);
    unsigned short* h0 = (unsigned short*)((char*)d_ws + H0_OFF);
    unsigned short* h1 = (unsigned short*)((char*)d_ws + H1_OFF);

    repack_weights<<<144, 256, 0, stream>>>(Wx, Wh, Wt);

    const int grid = B_ * HH;  // 512 blocks: one image row each
    lstm_step_mfma<true><<<grid, 256, 0, stream>>>(x, Wt, bias, out, cst, h0, h0, 0);
    for (int t = 1; t < T_; ++t) {
        unsigned short* hp = (t & 1) ? h0 : h1;   // written by step t-1
        unsigned short* hn = (t & 1) ? h1 : h0;
        lstm_step_mfma<false><<<grid, 256, 0, stream>>>(x, Wt, bias, out, cst, hp, hn, t);
    }
}